// Round 9
// baseline (259.133 us; speedup 1.0000x reference)
//
#include <hip/hip_runtime.h>
#include <hip/hip_bf16.h>
#include <hip/hip_fp16.h>
#include <math.h>

#define NN 100000
#define EE 1600000
#define ET 1700000   // E + N self-loops
#define HID 32

#define BKT_SHIFT 10
#define BKT_MASK 1023
#define NBKT 98            // ceil(NN / 1024)
#define EPB 4096           // edges per block in stage A
#define NBLK_A 416         // ceil(ET / EPB)
#define NBE 1024           // blocks for edge kernel

// ---- zero small int buffer ----
__global__ __launch_bounds__(128) void k_zero(int* __restrict__ p, int n) {
    int t = blockIdx.x * 128 + threadIdx.x;
    if (t < n) p[t] = 0;
}

// ---- stage A0: coarse bucket counts (LDS hist, one global atomic per block-bin) ----
__global__ __launch_bounds__(256) void k_bkt_count(const int* __restrict__ dst32, int* __restrict__ bucket_cnt) {
    __shared__ int h[NBKT];
    for (int i = threadIdx.x; i < NBKT; i += 256) h[i] = 0;
    __syncthreads();
    int base = blockIdx.x * EPB;
    for (int k = 0; k < EPB; k += 256) {
        int t = base + k + threadIdx.x;
        if (t < ET) atomicAdd(&h[dst32[t] >> BKT_SHIFT], 1);
    }
    __syncthreads();
    for (int i = threadIdx.x; i < NBKT; i += 256) {
        int c = h[i];
        if (c) atomicAdd(&bucket_cnt[i], c);
    }
}

// ---- stage A scan: exclusive scan of 98 bucket counts ----
__global__ __launch_bounds__(128) void k_bkt_scan(const int* __restrict__ bucket_cnt, int* __restrict__ bucket_base,
                                                  int* __restrict__ bucket_fill) {
    __shared__ int s[128];
    int t = threadIdx.x;
    int v = (t < NBKT) ? bucket_cnt[t] : 0;
    s[t] = v;
    for (int off = 1; off < 128; off <<= 1) {
        __syncthreads();
        int u = (t >= off) ? s[t - off] : 0;
        __syncthreads();
        s[t] += u;
    }
    __syncthreads();
    int ex = s[t] - v;
    if (t < NBKT) {
        bucket_base[t] = ex;
        bucket_fill[t] = ex;
    }
    if (t == 0) bucket_base[NBKT] = ET;
}

// ---- stage A1: scatter (src,dst) pairs + orig edge id into coarse bucket regions ----
__global__ __launch_bounds__(256) void k_bkt_scatter(const int* __restrict__ src32, const int* __restrict__ dst32,
                                                     int* __restrict__ bucket_fill, int2* __restrict__ pairs,
                                                     int* __restrict__ eidA) {
    __shared__ int h[NBKT];
    __shared__ int bbase[NBKT];
    for (int i = threadIdx.x; i < NBKT; i += 256) h[i] = 0;
    __syncthreads();
    int base = blockIdx.x * EPB;
    for (int k = 0; k < EPB; k += 256) {
        int t = base + k + threadIdx.x;
        if (t < ET) atomicAdd(&h[dst32[t] >> BKT_SHIFT], 1);
    }
    __syncthreads();
    for (int i = threadIdx.x; i < NBKT; i += 256) {
        int c = h[i];
        bbase[i] = c ? atomicAdd(&bucket_fill[i], c) : 0;
        h[i] = 0;  // becomes local fill counter (same thread owns bin -> no race)
    }
    __syncthreads();
    for (int k = 0; k < EPB; k += 256) {
        int t = base + k + threadIdx.x;
        if (t < ET) {
            int sv = src32[t], dv = dst32[t];
            int b = dv >> BKT_SHIFT;
            int off = atomicAdd(&h[b], 1);
            int slot = bbase[b] + off;
            pairs[slot] = make_int2(sv, dv);
            eidA[slot] = t;
        }
    }
}

// ---- stage B: per-bucket fine CSR (1024 nodes in LDS) + in-bucket scatter of src ----
__global__ __launch_bounds__(512) void k_bkt_csr(const int2* __restrict__ pairs, const int* __restrict__ bucket_base,
                                                 int* __restrict__ rowptr, int* __restrict__ src_sorted) {
    __shared__ int h[1024];
    __shared__ int tmp[512];
    int t = threadIdx.x;
    int b = blockIdx.x;
    int e0 = bucket_base[b], e1 = bucket_base[b + 1];
    int node0 = b << BKT_SHIFT;

    h[t] = 0;
    h[t + 512] = 0;
    __syncthreads();
    for (int e = e0 + t; e < e1; e += 512) atomicAdd(&h[pairs[e].y & BKT_MASK], 1);
    __syncthreads();

    int i0 = 2 * t, i1 = 2 * t + 1;
    int v0 = h[i0], v1 = h[i1];
    int s = v0 + v1;
    tmp[t] = s;
    for (int off = 1; off < 512; off <<= 1) {
        __syncthreads();
        int u = (t >= off) ? tmp[t - off] : 0;
        __syncthreads();
        tmp[t] += u;
    }
    __syncthreads();
    int excl = tmp[t] - s;
    h[i0] = excl;
    h[i1] = excl + v0;
    __syncthreads();

    for (int i = t; i < 1024; i += 512) {
        int node = node0 + i;
        if (node < NN) rowptr[node] = e0 + h[i];
    }
    if (b == 0 && t == 0) rowptr[NN] = ET;
    __syncthreads();

    for (int e = e0 + t; e < e1; e += 512) {
        int2 p = pairs[e];
        int sl = atomicAdd(&h[p.y & BKT_MASK], 1);
        src_sorted[e0 + sl] = p.x;
    }
}

// ---- helpers ----
__device__ __forceinline__ void acc4(uint2 r, float& c0, float& c1, float& c2, float& c3) {
    __half2 h0 = *reinterpret_cast<__half2*>(&r.x);
    __half2 h1 = *reinterpret_cast<__half2*>(&r.y);
    float2 f0 = __half22float2(h0);
    float2 f1 = __half22float2(h1);
    c0 += f0.x; c1 += f0.y; c2 += f1.x; c3 += f1.y;
}

// ---- layer 1a: thread-per-node scalar pull-agg of x0 ----
__global__ __launch_bounds__(256) void k_pull1a(const int* __restrict__ rowptr, const int* __restrict__ src_sorted,
                                                const float* __restrict__ x0, float* __restrict__ agg0) {
    int g = blockIdx.x * 256 + threadIdx.x;
    if (g >= NN) return;
    int e0 = rowptr[g], e1 = rowptr[g + 1];
    float a0 = x0[g], a1 = 0.f, a2 = 0.f, a3 = 0.f, a4 = 0.f, a5 = 0.f, a6 = 0.f, a7 = 0.f;
    int e = e0;
    for (; e + 8 <= e1; e += 8) {
        a0 += x0[src_sorted[e + 0]];
        a1 += x0[src_sorted[e + 1]];
        a2 += x0[src_sorted[e + 2]];
        a3 += x0[src_sorted[e + 3]];
        a4 += x0[src_sorted[e + 4]];
        a5 += x0[src_sorted[e + 5]];
        a6 += x0[src_sorted[e + 6]];
        a7 += x0[src_sorted[e + 7]];
    }
    for (; e < e1; ++e) a0 += x0[src_sorted[e]];
    agg0[g] = ((a0 + a1) + (a2 + a3)) + ((a4 + a5) + (a6 + a7));
}

// ---- layer 1b: expand agg0 -> h1 = relu(agg0*W1 + b1), 8 lanes/node ----
__global__ __launch_bounds__(256) void k_pull1b(const float* __restrict__ agg0, const float* __restrict__ W1,
                                                const float* __restrict__ b1, __half* __restrict__ hout) {
    int t = blockIdx.x * 256 + threadIdx.x;   // NN*8 threads
    int g = t >> 3, j = t & 7;
    float s = agg0[g];
    float o0 = fmaxf(fmaf(s, W1[4 * j + 0], b1[4 * j + 0]), 0.f);
    float o1 = fmaxf(fmaf(s, W1[4 * j + 1], b1[4 * j + 1]), 0.f);
    float o2 = fmaxf(fmaf(s, W1[4 * j + 2], b1[4 * j + 2]), 0.f);
    float o3 = fmaxf(fmaf(s, W1[4 * j + 3], b1[4 * j + 3]), 0.f);
    __half2 p0 = __floats2half2_rn(o0, o1);
    __half2 p1 = __floats2half2_rn(o2, o3);
    uint2 st = make_uint2(*reinterpret_cast<unsigned*>(&p0), *reinterpret_cast<unsigned*>(&p1));
    reinterpret_cast<uint2*>(hout)[(g << 3) + j] = st;
}

// ---- fused pull-agg + 32x32 matmul (+relu), 8 lanes/node, uint2 gathers, 8-deep ILP ----
template <int RELU>
__global__ __launch_bounds__(256) void k_agg_mm(const int* __restrict__ rowptr, const int* __restrict__ src_sorted,
                                                const __half* __restrict__ hin, const float* __restrict__ W,
                                                const float* __restrict__ b, __half* __restrict__ hout) {
    __shared__ float Wl[1024];
    for (int i = threadIdx.x; i < 1024; i += 256) Wl[i] = W[i];
    __syncthreads();
    int g = (blockIdx.x * 256 + threadIdx.x) >> 3;   // NN*8 threads, exact grid
    int j = threadIdx.x & 7;
    const uint2* tab = reinterpret_cast<const uint2*>(hin);
    int e0 = rowptr[g], e1 = rowptr[g + 1];
    float x0, x1, x2, x3;
    {
        uint2 r = tab[(g << 3) + j];
        __half2 h0 = *reinterpret_cast<__half2*>(&r.x);
        __half2 h1 = *reinterpret_cast<__half2*>(&r.y);
        float2 f0 = __half22float2(h0), f1 = __half22float2(h1);
        x0 = f0.x; x1 = f0.y; x2 = f1.x; x3 = f1.y;
    }
    float y0 = 0.f, y1 = 0.f, y2 = 0.f, y3 = 0.f;
    int e = e0;
    for (; e + 8 <= e1; e += 8) {
        int s0 = src_sorted[e + 0], s1 = src_sorted[e + 1], s2 = src_sorted[e + 2], s3 = src_sorted[e + 3];
        int s4 = src_sorted[e + 4], s5 = src_sorted[e + 5], s6 = src_sorted[e + 6], s7 = src_sorted[e + 7];
        uint2 r0 = tab[(s0 << 3) + j];
        uint2 r1 = tab[(s1 << 3) + j];
        uint2 r2 = tab[(s2 << 3) + j];
        uint2 r3 = tab[(s3 << 3) + j];
        uint2 r4 = tab[(s4 << 3) + j];
        uint2 r5 = tab[(s5 << 3) + j];
        uint2 r6 = tab[(s6 << 3) + j];
        uint2 r7 = tab[(s7 << 3) + j];
        acc4(r0, x0, x1, x2, x3);
        acc4(r1, y0, y1, y2, y3);
        acc4(r2, x0, x1, x2, x3);
        acc4(r3, y0, y1, y2, y3);
        acc4(r4, x0, x1, x2, x3);
        acc4(r5, y0, y1, y2, y3);
        acc4(r6, x0, x1, x2, x3);
        acc4(r7, y0, y1, y2, y3);
    }
    for (; e < e1; ++e) {
        uint2 r = tab[(src_sorted[e] << 3) + j];
        acc4(r, x0, x1, x2, x3);
    }
    x0 += y0; x1 += y1; x2 += y2; x3 += y3;

    float o0 = b[4 * j + 0], o1 = b[4 * j + 1], o2 = b[4 * j + 2], o3 = b[4 * j + 3];
#pragma unroll
    for (int k = 0; k < 8; ++k) {
        float f0 = __shfl(x0, k, 8);
        float f1 = __shfl(x1, k, 8);
        float f2 = __shfl(x2, k, 8);
        float f3 = __shfl(x3, k, 8);
        float4 w0 = *reinterpret_cast<const float4*>(&Wl[(4 * k + 0) * 32 + 4 * j]);
        float4 w1 = *reinterpret_cast<const float4*>(&Wl[(4 * k + 1) * 32 + 4 * j]);
        float4 w2 = *reinterpret_cast<const float4*>(&Wl[(4 * k + 2) * 32 + 4 * j]);
        float4 w3 = *reinterpret_cast<const float4*>(&Wl[(4 * k + 3) * 32 + 4 * j]);
        o0 = fmaf(f0, w0.x, o0); o1 = fmaf(f0, w0.y, o1); o2 = fmaf(f0, w0.z, o2); o3 = fmaf(f0, w0.w, o3);
        o0 = fmaf(f1, w1.x, o0); o1 = fmaf(f1, w1.y, o1); o2 = fmaf(f1, w1.z, o2); o3 = fmaf(f1, w1.w, o3);
        o0 = fmaf(f2, w2.x, o0); o1 = fmaf(f2, w2.y, o1); o2 = fmaf(f2, w2.z, o2); o3 = fmaf(f2, w2.w, o3);
        o0 = fmaf(f3, w3.x, o0); o1 = fmaf(f3, w3.y, o1); o2 = fmaf(f3, w3.z, o2); o3 = fmaf(f3, w3.w, o3);
    }
    if (RELU) {
        o0 = fmaxf(o0, 0.f); o1 = fmaxf(o1, 0.f); o2 = fmaxf(o2, 0.f); o3 = fmaxf(o3, 0.f);
    }
    __half2 p0 = __floats2half2_rn(o0, o1);
    __half2 p1 = __floats2half2_rn(o2, o3);
    uint2 st = make_uint2(*reinterpret_cast<unsigned*>(&p0), *reinterpret_cast<unsigned*>(&p1));
    reinterpret_cast<uint2*>(hout)[(g << 3) + j] = st;
}

// ---- layer 4 fused: pull-agg + W3 matmul + W5 projections -> u16 (b5 folded), v16 ----
__global__ __launch_bounds__(256) void k_agg_mm_proj(const int* __restrict__ rowptr, const int* __restrict__ src_sorted,
                                                     const __half* __restrict__ hin, const float* __restrict__ W3,
                                                     const float* __restrict__ b3,
                                                     const float* __restrict__ W5, const float* __restrict__ b5,
                                                     __half* __restrict__ u16, __half* __restrict__ v16) {
    __shared__ float W3l[1024];
    __shared__ float W5l[2048];
    for (int i = threadIdx.x; i < 1024; i += 256) W3l[i] = W3[i];
    for (int i = threadIdx.x; i < 2048; i += 256) W5l[i] = W5[i];
    __syncthreads();
    int g = (blockIdx.x * 256 + threadIdx.x) >> 3;
    int j = threadIdx.x & 7;
    const uint2* tab = reinterpret_cast<const uint2*>(hin);
    int e0 = rowptr[g], e1 = rowptr[g + 1];
    float x0, x1, x2, x3;
    {
        uint2 r = tab[(g << 3) + j];
        __half2 h0 = *reinterpret_cast<__half2*>(&r.x);
        __half2 h1 = *reinterpret_cast<__half2*>(&r.y);
        float2 f0 = __half22float2(h0), f1 = __half22float2(h1);
        x0 = f0.x; x1 = f0.y; x2 = f1.x; x3 = f1.y;
    }
    float y0 = 0.f, y1 = 0.f, y2 = 0.f, y3 = 0.f;
    int e = e0;
    for (; e + 8 <= e1; e += 8) {
        int s0 = src_sorted[e + 0], s1 = src_sorted[e + 1], s2 = src_sorted[e + 2], s3 = src_sorted[e + 3];
        int s4 = src_sorted[e + 4], s5 = src_sorted[e + 5], s6 = src_sorted[e + 6], s7 = src_sorted[e + 7];
        uint2 r0 = tab[(s0 << 3) + j];
        uint2 r1 = tab[(s1 << 3) + j];
        uint2 r2 = tab[(s2 << 3) + j];
        uint2 r3 = tab[(s3 << 3) + j];
        uint2 r4 = tab[(s4 << 3) + j];
        uint2 r5 = tab[(s5 << 3) + j];
        uint2 r6 = tab[(s6 << 3) + j];
        uint2 r7 = tab[(s7 << 3) + j];
        acc4(r0, x0, x1, x2, x3);
        acc4(r1, y0, y1, y2, y3);
        acc4(r2, x0, x1, x2, x3);
        acc4(r3, y0, y1, y2, y3);
        acc4(r4, x0, x1, x2, x3);
        acc4(r5, y0, y1, y2, y3);
        acc4(r6, x0, x1, x2, x3);
        acc4(r7, y0, y1, y2, y3);
    }
    for (; e < e1; ++e) {
        uint2 r = tab[(src_sorted[e] << 3) + j];
        acc4(r, x0, x1, x2, x3);
    }
    x0 += y0; x1 += y1; x2 += y2; x3 += y3;

    // x4 = agg . W3 + b3 (no relu)
    float o0 = b3[4 * j + 0], o1 = b3[4 * j + 1], o2 = b3[4 * j + 2], o3 = b3[4 * j + 3];
#pragma unroll
    for (int k = 0; k < 8; ++k) {
        float f0 = __shfl(x0, k, 8);
        float f1 = __shfl(x1, k, 8);
        float f2 = __shfl(x2, k, 8);
        float f3 = __shfl(x3, k, 8);
        float4 w0 = *reinterpret_cast<const float4*>(&W3l[(4 * k + 0) * 32 + 4 * j]);
        float4 w1 = *reinterpret_cast<const float4*>(&W3l[(4 * k + 1) * 32 + 4 * j]);
        float4 w2 = *reinterpret_cast<const float4*>(&W3l[(4 * k + 2) * 32 + 4 * j]);
        float4 w3 = *reinterpret_cast<const float4*>(&W3l[(4 * k + 3) * 32 + 4 * j]);
        o0 = fmaf(f0, w0.x, o0); o1 = fmaf(f0, w0.y, o1); o2 = fmaf(f0, w0.z, o2); o3 = fmaf(f0, w0.w, o3);
        o0 = fmaf(f1, w1.x, o0); o1 = fmaf(f1, w1.y, o1); o2 = fmaf(f1, w1.z, o2); o3 = fmaf(f1, w1.w, o3);
        o0 = fmaf(f2, w2.x, o0); o1 = fmaf(f2, w2.y, o1); o2 = fmaf(f2, w2.z, o2); o3 = fmaf(f2, w2.w, o3);
        o0 = fmaf(f3, w3.x, o0); o1 = fmaf(f3, w3.y, o1); o2 = fmaf(f3, w3.z, o2); o3 = fmaf(f3, w3.w, o3);
    }
    // u = x4 . W5[0:32,:] + b5 ; v = x4 . W5[32:64,:]
    float u0 = b5[4 * j + 0], u1 = b5[4 * j + 1], u2 = b5[4 * j + 2], u3 = b5[4 * j + 3];
    float v0 = 0.f, v1 = 0.f, v2 = 0.f, v3 = 0.f;
#pragma unroll
    for (int k = 0; k < 8; ++k) {
        float f0 = __shfl(o0, k, 8);
        float f1 = __shfl(o1, k, 8);
        float f2 = __shfl(o2, k, 8);
        float f3 = __shfl(o3, k, 8);
        float4 a0 = *reinterpret_cast<const float4*>(&W5l[(4 * k + 0) * 32 + 4 * j]);
        float4 a1 = *reinterpret_cast<const float4*>(&W5l[(4 * k + 1) * 32 + 4 * j]);
        float4 a2 = *reinterpret_cast<const float4*>(&W5l[(4 * k + 2) * 32 + 4 * j]);
        float4 a3 = *reinterpret_cast<const float4*>(&W5l[(4 * k + 3) * 32 + 4 * j]);
        u0 = fmaf(f0, a0.x, u0); u1 = fmaf(f0, a0.y, u1); u2 = fmaf(f0, a0.z, u2); u3 = fmaf(f0, a0.w, u3);
        u0 = fmaf(f1, a1.x, u0); u1 = fmaf(f1, a1.y, u1); u2 = fmaf(f1, a1.z, u2); u3 = fmaf(f1, a1.w, u3);
        u0 = fmaf(f2, a2.x, u0); u1 = fmaf(f2, a2.y, u1); u2 = fmaf(f2, a2.z, u2); u3 = fmaf(f2, a2.w, u3);
        u0 = fmaf(f3, a3.x, u0); u1 = fmaf(f3, a3.y, u1); u2 = fmaf(f3, a3.z, u2); u3 = fmaf(f3, a3.w, u3);
        float4 c0 = *reinterpret_cast<const float4*>(&W5l[(32 + 4 * k + 0) * 32 + 4 * j]);
        float4 c1 = *reinterpret_cast<const float4*>(&W5l[(32 + 4 * k + 1) * 32 + 4 * j]);
        float4 c2 = *reinterpret_cast<const float4*>(&W5l[(32 + 4 * k + 2) * 32 + 4 * j]);
        float4 c3 = *reinterpret_cast<const float4*>(&W5l[(32 + 4 * k + 3) * 32 + 4 * j]);
        v0 = fmaf(f0, c0.x, v0); v1 = fmaf(f0, c0.y, v1); v2 = fmaf(f0, c0.z, v2); v3 = fmaf(f0, c0.w, v3);
        v0 = fmaf(f1, c1.x, v0); v1 = fmaf(f1, c1.y, v1); v2 = fmaf(f1, c1.z, v2); v3 = fmaf(f1, c1.w, v3);
        v0 = fmaf(f2, c2.x, v0); v1 = fmaf(f2, c2.y, v1); v2 = fmaf(f2, c2.z, v2); v3 = fmaf(f2, c2.w, v3);
        v0 = fmaf(f3, c3.x, v0); v1 = fmaf(f3, c3.y, v1); v2 = fmaf(f3, c3.z, v2); v3 = fmaf(f3, c3.w, v3);
    }
    __half2 pu0 = __floats2half2_rn(u0, u1);
    __half2 pu1 = __floats2half2_rn(u2, u3);
    uint2 su = make_uint2(*reinterpret_cast<unsigned*>(&pu0), *reinterpret_cast<unsigned*>(&pu1));
    reinterpret_cast<uint2*>(u16)[(g << 3) + j] = su;
    __half2 pv0 = __floats2half2_rn(v0, v1);
    __half2 pv1 = __floats2half2_rn(v2, v3);
    uint2 sv = make_uint2(*reinterpret_cast<unsigned*>(&pv0), *reinterpret_cast<unsigned*>(&pv1));
    reinterpret_cast<uint2*>(v16)[(g << 3) + j] = sv;
}

// ---- per-edge in dst-sorted order: pd + register-resident img accumulation ----
__global__ __launch_bounds__(256) void k_edge2(const int2* __restrict__ pairs, const int* __restrict__ eidA,
                                               const __half* __restrict__ u16, const __half* __restrict__ v16,
                                               const float* __restrict__ W6, const float* __restrict__ b6,
                                               float* __restrict__ pd_out, float* __restrict__ partial) {
    float acc[25];
#pragma unroll
    for (int i = 0; i < 25; ++i) acc[i] = 0.f;
    float b60 = b6[0], b61 = b6[1];
    const float inv = 3.5355339059327378f;  // 1/(0.2*sqrt(2))

    int t0 = blockIdx.x * 256 + threadIdx.x;
    const int stride = NBE * 256;
    for (int e = t0; e < ET; e += stride) {
        int2 p = pairs[e];
        int eid = eidA[e];
        if (eid < EE) {
            const uint4* pu = reinterpret_cast<const uint4*>(u16 + ((size_t)p.x << 5));
            const uint4* pv = reinterpret_cast<const uint4*>(v16 + ((size_t)p.y << 5));
            float pd0 = b60, pd1 = b61;
#pragma unroll
            for (int q = 0; q < 4; ++q) {
                uint4 ua = pu[q];
                uint4 vb = pv[q];
                const __half2* ah = reinterpret_cast<const __half2*>(&ua);
                const __half2* bh = reinterpret_cast<const __half2*>(&vb);
#pragma unroll
                for (int r = 0; r < 4; ++r) {
                    float2 f = __half22float2(__hadd2(ah[r], bh[r]));
                    int jj = q * 8 + 2 * r;
                    float h0 = f.x >= 0.f ? f.x : 0.1f * f.x;
                    float h1 = f.y >= 0.f ? f.y : 0.1f * f.y;
                    pd0 = fmaf(h0, W6[2 * jj + 0], pd0);
                    pd1 = fmaf(h0, W6[2 * jj + 1], pd1);
                    pd0 = fmaf(h1, W6[2 * (jj + 1) + 0], pd0);
                    pd1 = fmaf(h1, W6[2 * (jj + 1) + 1], pd1);
                }
            }
            reinterpret_cast<float2*>(pd_out)[eid] = make_float2(pd0, pd1);

            float pers = pd1 - pd0;
            float cb[6], cp[6];
#pragma unroll
            for (int i = 0; i < 6; ++i) {
                float te = 0.2f * (float)i;
                cb[i] = erff((te - pd0) * inv);
                cp[i] = erff((te - pers) * inv);
            }
            // img(i,jj) += pers * (0.5*dcb) * (0.5*dcp)
#pragma unroll
            for (int i = 0; i < 5; ++i) {
                float pdb = 0.25f * pers * (cb[i + 1] - cb[i]);
#pragma unroll
                for (int jj = 0; jj < 5; ++jj)
                    acc[i * 5 + jj] = fmaf(pdb, cp[jj + 1] - cp[jj], acc[i * 5 + jj]);
            }
        }
    }

    int lane = threadIdx.x & 63;
    int wv = threadIdx.x >> 6;
    __shared__ float sacc[4][25];
#pragma unroll
    for (int i = 0; i < 25; ++i) {
        float v = acc[i];
        v += __shfl_down(v, 32);
        v += __shfl_down(v, 16);
        v += __shfl_down(v, 8);
        v += __shfl_down(v, 4);
        v += __shfl_down(v, 2);
        v += __shfl_down(v, 1);
        if (lane == 0) sacc[wv][i] = v;
    }
    __syncthreads();
    if (threadIdx.x < 25) {
        partial[(size_t)blockIdx.x * 25 + threadIdx.x] =
            sacc[0][threadIdx.x] + sacc[1][threadIdx.x] + sacc[2][threadIdx.x] + sacc[3][threadIdx.x];
    }
}

// ---- deterministic final reduction of block partials per bin ----
__global__ __launch_bounds__(256) void k_img(const float* __restrict__ partial, float* __restrict__ img) {
    int bin = blockIdx.x;  // 25 blocks
    float s = 0.f;
    for (int k = threadIdx.x; k < NBE; k += 256) s += partial[(size_t)k * 25 + bin];
    s += __shfl_down(s, 32);
    s += __shfl_down(s, 16);
    s += __shfl_down(s, 8);
    s += __shfl_down(s, 4);
    s += __shfl_down(s, 2);
    s += __shfl_down(s, 1);
    __shared__ float wsum[4];
    if ((threadIdx.x & 63) == 0) wsum[threadIdx.x >> 6] = s;
    __syncthreads();
    if (threadIdx.x == 0) img[bin] = wsum[0] + wsum[1] + wsum[2] + wsum[3];
}

extern "C" void kernel_launch(void* const* d_in, const int* in_sizes, int n_in,
                              void* d_out, int out_size, void* d_ws, size_t ws_size,
                              hipStream_t stream) {
    const float* x0 = (const float*)d_in[0];
    // Harness converts integer inputs to int32: edge_index0 is (2, ET) int32.
    const int* src32 = (const int*)d_in[1];
    const int* dst32 = src32 + ET;
    const float* W1 = (const float*)d_in[2];
    const float* b1 = (const float*)d_in[3];
    const float* W2 = (const float*)d_in[4];
    const float* b2 = (const float*)d_in[5];
    const float* W4 = (const float*)d_in[6];
    const float* b4 = (const float*)d_in[7];
    const float* W3 = (const float*)d_in[8];
    const float* b3 = (const float*)d_in[9];
    const float* W5 = (const float*)d_in[10];
    const float* b5 = (const float*)d_in[11];
    const float* W6 = (const float*)d_in[12];
    const float* b6 = (const float*)d_in[13];
    float* out = (float*)d_out;

    char* w = (char*)d_ws;
    int2* pairs = (int2*)w;                          // ET int2
    int* eidA = (int*)(pairs + ET);                  // ET
    int* bucket_cnt = eidA + ET;                     // NBKT
    int* bucket_base = bucket_cnt + NBKT;            // NBKT+1
    int* bucket_fill = bucket_base + NBKT + 1;       // NBKT
    int* rowptr = bucket_fill + NBKT;                // NN+1
    int* src_sorted = rowptr + NN + 1;               // ET
    size_t off = ((size_t)((char*)(src_sorted + ET) - w) + 63) & ~(size_t)63;
    __half* bufA = (__half*)(w + off);               // NN*32 halfs
    __half* bufB = bufA + (size_t)NN * 32;           // NN*32 halfs
    __half* u16 = bufB + (size_t)NN * 32;            // NN*32 halfs
    __half* v16 = u16 + (size_t)NN * 32;             // NN*32 halfs
    float* agg0 = (float*)(v16 + (size_t)NN * 32);   // NN floats
    float* partial = agg0 + NN;                      // NBE*25 floats

    // ---- build CSR via coarse-bucket counting sort (carrying orig edge id) ----
    k_zero<<<1, 128, 0, stream>>>(bucket_cnt, NBKT);
    k_bkt_count<<<NBLK_A, 256, 0, stream>>>(dst32, bucket_cnt);
    k_bkt_scan<<<1, 128, 0, stream>>>(bucket_cnt, bucket_base, bucket_fill);
    k_bkt_scatter<<<NBLK_A, 256, 0, stream>>>(src32, dst32, bucket_fill, pairs, eidA);
    k_bkt_csr<<<NBKT, 512, 0, stream>>>(pairs, bucket_base, rowptr, src_sorted);

    // ---- layer 1 ----
    k_pull1a<<<(NN + 255) / 256, 256, 0, stream>>>(rowptr, src_sorted, x0, agg0);
    k_pull1b<<<NN * 8 / 256, 256, 0, stream>>>(agg0, W1, b1, bufA);
    // ---- layers 2-3 ----
    k_agg_mm<1><<<NN * 8 / 256, 256, 0, stream>>>(rowptr, src_sorted, bufA, W2, b2, bufB);
    k_agg_mm<1><<<NN * 8 / 256, 256, 0, stream>>>(rowptr, src_sorted, bufB, W4, b4, bufA);
    // ---- layer 4 + W5 projections ----
    k_agg_mm_proj<<<NN * 8 / 256, 256, 0, stream>>>(rowptr, src_sorted, bufA, W3, b3, W5, b5, u16, v16);

    // ---- edge MLP + persistence image (dst-sorted order, scattered pd by eid) ----
    k_edge2<<<NBE, 256, 0, stream>>>(pairs, eidA, u16, v16, W6, b6, out, partial);
    k_img<<<25, 256, 0, stream>>>(partial, out + 2 * (size_t)EE);
}

// Round 10
// 253.619 us; speedup vs baseline: 1.0217x; 1.0217x over previous
//
#include <hip/hip_runtime.h>
#include <hip/hip_bf16.h>
#include <hip/hip_fp16.h>
#include <math.h>

#define NN 100000
#define EE 1600000
#define ET 1700000   // E + N self-loops
#define HID 32

#define BKT_SHIFT 10
#define BKT_MASK 1023
#define NBKT 98            // ceil(NN / 1024)
#define EPB 4096           // edges per block in stage A
#define NBLK_A 416         // ceil(ET / EPB)

// ---- zero small int buffer ----
__global__ __launch_bounds__(128) void k_zero(int* __restrict__ p, int n) {
    int t = blockIdx.x * 128 + threadIdx.x;
    if (t < n) p[t] = 0;
}

// ---- stage A0: coarse bucket counts (LDS hist, one global atomic per block-bin) ----
__global__ __launch_bounds__(256) void k_bkt_count(const int* __restrict__ dst32, int* __restrict__ bucket_cnt) {
    __shared__ int h[NBKT];
    for (int i = threadIdx.x; i < NBKT; i += 256) h[i] = 0;
    __syncthreads();
    int base = blockIdx.x * EPB;
    for (int k = 0; k < EPB; k += 256) {
        int t = base + k + threadIdx.x;
        if (t < ET) atomicAdd(&h[dst32[t] >> BKT_SHIFT], 1);
    }
    __syncthreads();
    for (int i = threadIdx.x; i < NBKT; i += 256) {
        int c = h[i];
        if (c) atomicAdd(&bucket_cnt[i], c);
    }
}

// ---- stage A scan: exclusive scan of 98 bucket counts ----
__global__ __launch_bounds__(128) void k_bkt_scan(const int* __restrict__ bucket_cnt, int* __restrict__ bucket_base,
                                                  int* __restrict__ bucket_fill) {
    __shared__ int s[128];
    int t = threadIdx.x;
    int v = (t < NBKT) ? bucket_cnt[t] : 0;
    s[t] = v;
    for (int off = 1; off < 128; off <<= 1) {
        __syncthreads();
        int u = (t >= off) ? s[t - off] : 0;
        __syncthreads();
        s[t] += u;
    }
    __syncthreads();
    int ex = s[t] - v;
    if (t < NBKT) {
        bucket_base[t] = ex;
        bucket_fill[t] = ex;
    }
    if (t == 0) bucket_base[NBKT] = ET;
}

// ---- stage A1: scatter (src,dst) pairs into coarse bucket regions ----
__global__ __launch_bounds__(256) void k_bkt_scatter(const int* __restrict__ src32, const int* __restrict__ dst32,
                                                     int* __restrict__ bucket_fill, int2* __restrict__ pairs) {
    __shared__ int h[NBKT];
    __shared__ int bbase[NBKT];
    for (int i = threadIdx.x; i < NBKT; i += 256) h[i] = 0;
    __syncthreads();
    int base = blockIdx.x * EPB;
    for (int k = 0; k < EPB; k += 256) {
        int t = base + k + threadIdx.x;
        if (t < ET) atomicAdd(&h[dst32[t] >> BKT_SHIFT], 1);
    }
    __syncthreads();
    for (int i = threadIdx.x; i < NBKT; i += 256) {
        int c = h[i];
        bbase[i] = c ? atomicAdd(&bucket_fill[i], c) : 0;
        h[i] = 0;  // becomes local fill counter (same thread owns bin -> no race)
    }
    __syncthreads();
    for (int k = 0; k < EPB; k += 256) {
        int t = base + k + threadIdx.x;
        if (t < ET) {
            int sv = src32[t], dv = dst32[t];
            int b = dv >> BKT_SHIFT;
            int off = atomicAdd(&h[b], 1);
            pairs[bbase[b] + off] = make_int2(sv, dv);
        }
    }
}

// ---- stage B: per-bucket fine CSR (1024 nodes in LDS) + in-bucket scatter of src ----
__global__ __launch_bounds__(512) void k_bkt_csr(const int2* __restrict__ pairs, const int* __restrict__ bucket_base,
                                                 int* __restrict__ rowptr, int* __restrict__ src_sorted) {
    __shared__ int h[1024];
    __shared__ int tmp[512];
    int t = threadIdx.x;
    int b = blockIdx.x;
    int e0 = bucket_base[b], e1 = bucket_base[b + 1];
    int node0 = b << BKT_SHIFT;

    h[t] = 0;
    h[t + 512] = 0;
    __syncthreads();
    for (int e = e0 + t; e < e1; e += 512) atomicAdd(&h[pairs[e].y & BKT_MASK], 1);
    __syncthreads();

    int i0 = 2 * t, i1 = 2 * t + 1;
    int v0 = h[i0], v1 = h[i1];
    int s = v0 + v1;
    tmp[t] = s;
    for (int off = 1; off < 512; off <<= 1) {
        __syncthreads();
        int u = (t >= off) ? tmp[t - off] : 0;
        __syncthreads();
        tmp[t] += u;
    }
    __syncthreads();
    int excl = tmp[t] - s;
    h[i0] = excl;
    h[i1] = excl + v0;
    __syncthreads();

    for (int i = t; i < 1024; i += 512) {
        int node = node0 + i;
        if (node < NN) rowptr[node] = e0 + h[i];
    }
    if (b == 0 && t == 0) rowptr[NN] = ET;
    __syncthreads();

    for (int e = e0 + t; e < e1; e += 512) {
        int2 p = pairs[e];
        int sl = atomicAdd(&h[p.y & BKT_MASK], 1);
        src_sorted[e0 + sl] = p.x;
    }
}

// ---- helpers ----
__device__ __forceinline__ void acc8(uint4 r, float* c) {
    float2 f0 = __half22float2(*reinterpret_cast<__half2*>(&r.x));
    float2 f1 = __half22float2(*reinterpret_cast<__half2*>(&r.y));
    float2 f2 = __half22float2(*reinterpret_cast<__half2*>(&r.z));
    float2 f3 = __half22float2(*reinterpret_cast<__half2*>(&r.w));
    c[0] += f0.x; c[1] += f0.y; c[2] += f1.x; c[3] += f1.y;
    c[4] += f2.x; c[5] += f2.y; c[6] += f3.x; c[7] += f3.y;
}

// ---- layer 1a: thread-per-node scalar pull-agg of x0 ----
__global__ __launch_bounds__(256) void k_pull1a(const int* __restrict__ rowptr, const int* __restrict__ src_sorted,
                                                const float* __restrict__ x0, float* __restrict__ agg0) {
    int g = blockIdx.x * 256 + threadIdx.x;
    if (g >= NN) return;
    int e0 = rowptr[g], e1 = rowptr[g + 1];
    float a0 = x0[g], a1 = 0.f, a2 = 0.f, a3 = 0.f, a4 = 0.f, a5 = 0.f, a6 = 0.f, a7 = 0.f;
    int e = e0;
    for (; e + 8 <= e1; e += 8) {
        a0 += x0[src_sorted[e + 0]];
        a1 += x0[src_sorted[e + 1]];
        a2 += x0[src_sorted[e + 2]];
        a3 += x0[src_sorted[e + 3]];
        a4 += x0[src_sorted[e + 4]];
        a5 += x0[src_sorted[e + 5]];
        a6 += x0[src_sorted[e + 6]];
        a7 += x0[src_sorted[e + 7]];
    }
    for (; e < e1; ++e) a0 += x0[src_sorted[e]];
    agg0[g] = ((a0 + a1) + (a2 + a3)) + ((a4 + a5) + (a6 + a7));
}

// ---- layer 1b: expand agg0 -> h1 = relu(agg0*W1 + b1), 8 lanes/node ----
__global__ __launch_bounds__(256) void k_pull1b(const float* __restrict__ agg0, const float* __restrict__ W1,
                                                const float* __restrict__ b1, __half* __restrict__ hout) {
    int t = blockIdx.x * 256 + threadIdx.x;   // NN*8 threads
    int g = t >> 3, j = t & 7;
    float s = agg0[g];
    float o0 = fmaxf(fmaf(s, W1[4 * j + 0], b1[4 * j + 0]), 0.f);
    float o1 = fmaxf(fmaf(s, W1[4 * j + 1], b1[4 * j + 1]), 0.f);
    float o2 = fmaxf(fmaf(s, W1[4 * j + 2], b1[4 * j + 2]), 0.f);
    float o3 = fmaxf(fmaf(s, W1[4 * j + 3], b1[4 * j + 3]), 0.f);
    __half2 p0 = __floats2half2_rn(o0, o1);
    __half2 p1 = __floats2half2_rn(o2, o3);
    uint2 st = make_uint2(*reinterpret_cast<unsigned*>(&p0), *reinterpret_cast<unsigned*>(&p1));
    reinterpret_cast<uint2*>(hout)[(g << 3) + j] = st;
}

// ---- fused pull-agg + 32x32 matmul (+relu), 4 lanes/node, uint4 gathers, 8-deep ILP ----
template <int RELU>
__global__ __launch_bounds__(256) void k_agg_mm(const int* __restrict__ rowptr, const int* __restrict__ src_sorted,
                                                const __half* __restrict__ hin, const float* __restrict__ W,
                                                const float* __restrict__ b, __half* __restrict__ hout) {
    __shared__ float Wl[1024];
    for (int i = threadIdx.x; i < 1024; i += 256) Wl[i] = W[i];
    __syncthreads();
    int g = (blockIdx.x * 256 + threadIdx.x) >> 2;   // 64 nodes/block
    if (g >= NN) return;
    int j = threadIdx.x & 3;
    const uint4* tab = reinterpret_cast<const uint4*>(hin);
    int e0 = rowptr[g], e1 = rowptr[g + 1];
    float x[8], y[8];
#pragma unroll
    for (int i = 0; i < 8; ++i) { x[i] = 0.f; y[i] = 0.f; }
    acc8(tab[(g << 2) + j], x);  // self term
    int e = e0;
    for (; e + 8 <= e1; e += 8) {
        int s0 = src_sorted[e + 0], s1 = src_sorted[e + 1], s2 = src_sorted[e + 2], s3 = src_sorted[e + 3];
        int s4 = src_sorted[e + 4], s5 = src_sorted[e + 5], s6 = src_sorted[e + 6], s7 = src_sorted[e + 7];
        uint4 r0 = tab[(s0 << 2) + j];
        uint4 r1 = tab[(s1 << 2) + j];
        uint4 r2 = tab[(s2 << 2) + j];
        uint4 r3 = tab[(s3 << 2) + j];
        uint4 r4 = tab[(s4 << 2) + j];
        uint4 r5 = tab[(s5 << 2) + j];
        uint4 r6 = tab[(s6 << 2) + j];
        uint4 r7 = tab[(s7 << 2) + j];
        acc8(r0, x); acc8(r1, y); acc8(r2, x); acc8(r3, y);
        acc8(r4, x); acc8(r5, y); acc8(r6, x); acc8(r7, y);
    }
    for (; e < e1; ++e) acc8(tab[(src_sorted[e] << 2) + j], x);
#pragma unroll
    for (int i = 0; i < 8; ++i) x[i] += y[i];

    float o[8];
#pragma unroll
    for (int i = 0; i < 8; ++i) o[i] = b[8 * j + i];
#pragma unroll
    for (int sl = 0; sl < 4; ++sl) {
#pragma unroll
        for (int r = 0; r < 8; ++r) {
            float xk = __shfl(x[r], sl, 4);
            int k = 8 * sl + r;
            float4 w0 = *reinterpret_cast<const float4*>(&Wl[k * 32 + 8 * j]);
            float4 w1 = *reinterpret_cast<const float4*>(&Wl[k * 32 + 8 * j + 4]);
            o[0] = fmaf(xk, w0.x, o[0]); o[1] = fmaf(xk, w0.y, o[1]);
            o[2] = fmaf(xk, w0.z, o[2]); o[3] = fmaf(xk, w0.w, o[3]);
            o[4] = fmaf(xk, w1.x, o[4]); o[5] = fmaf(xk, w1.y, o[5]);
            o[6] = fmaf(xk, w1.z, o[6]); o[7] = fmaf(xk, w1.w, o[7]);
        }
    }
    if (RELU) {
#pragma unroll
        for (int i = 0; i < 8; ++i) o[i] = fmaxf(o[i], 0.f);
    }
    __half2 p0 = __floats2half2_rn(o[0], o[1]);
    __half2 p1 = __floats2half2_rn(o[2], o[3]);
    __half2 p2 = __floats2half2_rn(o[4], o[5]);
    __half2 p3 = __floats2half2_rn(o[6], o[7]);
    uint4 st = make_uint4(*reinterpret_cast<unsigned*>(&p0), *reinterpret_cast<unsigned*>(&p1),
                          *reinterpret_cast<unsigned*>(&p2), *reinterpret_cast<unsigned*>(&p3));
    reinterpret_cast<uint4*>(hout)[(g << 2) + j] = st;
}

// ---- layer 4 fused: pull-agg + W3 matmul + W5 projections -> u16 (b5 folded), v16 ----
__global__ __launch_bounds__(256) void k_agg_mm_proj(const int* __restrict__ rowptr, const int* __restrict__ src_sorted,
                                                     const __half* __restrict__ hin, const float* __restrict__ W3,
                                                     const float* __restrict__ b3,
                                                     const float* __restrict__ W5, const float* __restrict__ b5,
                                                     __half* __restrict__ u16, __half* __restrict__ v16) {
    __shared__ float W3l[1024];
    __shared__ float W5l[2048];
    for (int i = threadIdx.x; i < 1024; i += 256) W3l[i] = W3[i];
    for (int i = threadIdx.x; i < 2048; i += 256) W5l[i] = W5[i];
    __syncthreads();
    int g = (blockIdx.x * 256 + threadIdx.x) >> 2;
    if (g >= NN) return;
    int j = threadIdx.x & 3;
    const uint4* tab = reinterpret_cast<const uint4*>(hin);
    int e0 = rowptr[g], e1 = rowptr[g + 1];
    float x[8], y[8];
#pragma unroll
    for (int i = 0; i < 8; ++i) { x[i] = 0.f; y[i] = 0.f; }
    acc8(tab[(g << 2) + j], x);  // self term
    int e = e0;
    for (; e + 8 <= e1; e += 8) {
        int s0 = src_sorted[e + 0], s1 = src_sorted[e + 1], s2 = src_sorted[e + 2], s3 = src_sorted[e + 3];
        int s4 = src_sorted[e + 4], s5 = src_sorted[e + 5], s6 = src_sorted[e + 6], s7 = src_sorted[e + 7];
        uint4 r0 = tab[(s0 << 2) + j];
        uint4 r1 = tab[(s1 << 2) + j];
        uint4 r2 = tab[(s2 << 2) + j];
        uint4 r3 = tab[(s3 << 2) + j];
        uint4 r4 = tab[(s4 << 2) + j];
        uint4 r5 = tab[(s5 << 2) + j];
        uint4 r6 = tab[(s6 << 2) + j];
        uint4 r7 = tab[(s7 << 2) + j];
        acc8(r0, x); acc8(r1, y); acc8(r2, x); acc8(r3, y);
        acc8(r4, x); acc8(r5, y); acc8(r6, x); acc8(r7, y);
    }
    for (; e < e1; ++e) acc8(tab[(src_sorted[e] << 2) + j], x);
#pragma unroll
    for (int i = 0; i < 8; ++i) x[i] += y[i];

    // x4 = agg . W3 + b3 (no relu)
    float o[8];
#pragma unroll
    for (int i = 0; i < 8; ++i) o[i] = b3[8 * j + i];
#pragma unroll
    for (int sl = 0; sl < 4; ++sl) {
#pragma unroll
        for (int r = 0; r < 8; ++r) {
            float xk = __shfl(x[r], sl, 4);
            int k = 8 * sl + r;
            float4 w0 = *reinterpret_cast<const float4*>(&W3l[k * 32 + 8 * j]);
            float4 w1 = *reinterpret_cast<const float4*>(&W3l[k * 32 + 8 * j + 4]);
            o[0] = fmaf(xk, w0.x, o[0]); o[1] = fmaf(xk, w0.y, o[1]);
            o[2] = fmaf(xk, w0.z, o[2]); o[3] = fmaf(xk, w0.w, o[3]);
            o[4] = fmaf(xk, w1.x, o[4]); o[5] = fmaf(xk, w1.y, o[5]);
            o[6] = fmaf(xk, w1.z, o[6]); o[7] = fmaf(xk, w1.w, o[7]);
        }
    }
    // u = x4 . W5[0:32,:] + b5 ; v = x4 . W5[32:64,:]
    float u[8], v[8];
#pragma unroll
    for (int i = 0; i < 8; ++i) { u[i] = b5[8 * j + i]; v[i] = 0.f; }
#pragma unroll
    for (int sl = 0; sl < 4; ++sl) {
#pragma unroll
        for (int r = 0; r < 8; ++r) {
            float xk = __shfl(o[r], sl, 4);
            int k = 8 * sl + r;
            float4 a0 = *reinterpret_cast<const float4*>(&W5l[k * 32 + 8 * j]);
            float4 a1 = *reinterpret_cast<const float4*>(&W5l[k * 32 + 8 * j + 4]);
            u[0] = fmaf(xk, a0.x, u[0]); u[1] = fmaf(xk, a0.y, u[1]);
            u[2] = fmaf(xk, a0.z, u[2]); u[3] = fmaf(xk, a0.w, u[3]);
            u[4] = fmaf(xk, a1.x, u[4]); u[5] = fmaf(xk, a1.y, u[5]);
            u[6] = fmaf(xk, a1.z, u[6]); u[7] = fmaf(xk, a1.w, u[7]);
            float4 c0 = *reinterpret_cast<const float4*>(&W5l[(32 + k) * 32 + 8 * j]);
            float4 c1 = *reinterpret_cast<const float4*>(&W5l[(32 + k) * 32 + 8 * j + 4]);
            v[0] = fmaf(xk, c0.x, v[0]); v[1] = fmaf(xk, c0.y, v[1]);
            v[2] = fmaf(xk, c0.z, v[2]); v[3] = fmaf(xk, c0.w, v[3]);
            v[4] = fmaf(xk, c1.x, v[4]); v[5] = fmaf(xk, c1.y, v[5]);
            v[6] = fmaf(xk, c1.z, v[6]); v[7] = fmaf(xk, c1.w, v[7]);
        }
    }
    __half2 pu0 = __floats2half2_rn(u[0], u[1]);
    __half2 pu1 = __floats2half2_rn(u[2], u[3]);
    __half2 pu2 = __floats2half2_rn(u[4], u[5]);
    __half2 pu3 = __floats2half2_rn(u[6], u[7]);
    uint4 su = make_uint4(*reinterpret_cast<unsigned*>(&pu0), *reinterpret_cast<unsigned*>(&pu1),
                          *reinterpret_cast<unsigned*>(&pu2), *reinterpret_cast<unsigned*>(&pu3));
    reinterpret_cast<uint4*>(u16)[(g << 2) + j] = su;
    __half2 pv0 = __floats2half2_rn(v[0], v[1]);
    __half2 pv1 = __floats2half2_rn(v[2], v[3]);
    __half2 pv2 = __floats2half2_rn(v[4], v[5]);
    __half2 pv3 = __floats2half2_rn(v[6], v[7]);
    uint4 sv = make_uint4(*reinterpret_cast<unsigned*>(&pv0), *reinterpret_cast<unsigned*>(&pv1),
                          *reinterpret_cast<unsigned*>(&pv2), *reinterpret_cast<unsigned*>(&pv3));
    reinterpret_cast<uint4*>(v16)[(g << 2) + j] = sv;
}

// ---- per-edge (2 edges/thread): h = prelu(u[s]+v[d]); pd = h.W6 + b6; img partials ----
__device__ __forceinline__ void edge_pd(const uint4* pu, const uint4* pv, const float* W6,
                                        float b60, float b61, float& pd0, float& pd1) {
    pd0 = b60; pd1 = b61;
#pragma unroll
    for (int q = 0; q < 4; ++q) {
        uint4 ua = pu[q];
        uint4 vb = pv[q];
        const __half2* ah = reinterpret_cast<const __half2*>(&ua);
        const __half2* bh = reinterpret_cast<const __half2*>(&vb);
#pragma unroll
        for (int r = 0; r < 4; ++r) {
            float2 f = __half22float2(__hadd2(ah[r], bh[r]));
            int jj = q * 8 + 2 * r;
            float h0 = f.x >= 0.f ? f.x : 0.1f * f.x;
            float h1 = f.y >= 0.f ? f.y : 0.1f * f.y;
            pd0 = fmaf(h0, W6[2 * jj + 0], pd0);
            pd1 = fmaf(h0, W6[2 * jj + 1], pd1);
            pd0 = fmaf(h1, W6[2 * (jj + 1) + 0], pd0);
            pd1 = fmaf(h1, W6[2 * (jj + 1) + 1], pd1);
        }
    }
}

__global__ __launch_bounds__(256) void k_edge(const int* __restrict__ src32, const int* __restrict__ dst32,
                                              const __half* __restrict__ u16, const __half* __restrict__ v16,
                                              const float* __restrict__ W6, const float* __restrict__ b6,
                                              float* __restrict__ pd_out, float* __restrict__ partial) {
    int ea = blockIdx.x * 512 + threadIdx.x;   // EE divisible by 512
    int eb = ea + 256;
    int sa = src32[ea], da = dst32[ea];
    int sb = src32[eb], db = dst32[eb];
    const uint4* pua = reinterpret_cast<const uint4*>(u16 + ((size_t)sa << 5));
    const uint4* pva = reinterpret_cast<const uint4*>(v16 + ((size_t)da << 5));
    const uint4* pub = reinterpret_cast<const uint4*>(u16 + ((size_t)sb << 5));
    const uint4* pvb = reinterpret_cast<const uint4*>(v16 + ((size_t)db << 5));
    float b60 = b6[0], b61 = b6[1];

    float pda0, pda1, pdb0, pdb1;
    edge_pd(pua, pva, W6, b60, b61, pda0, pda1);
    edge_pd(pub, pvb, W6, b60, b61, pdb0, pdb1);
    reinterpret_cast<float2*>(pd_out)[ea] = make_float2(pda0, pda1);
    reinterpret_cast<float2*>(pd_out)[eb] = make_float2(pdb0, pdb1);

    float persA = pda1 - pda0;
    float persB = pdb1 - pdb0;
    const float inv = 3.5355339059327378f;  // 1/(0.2*sqrt(2))
    float cbA[6], cpA[6], cbB[6], cpB[6];
#pragma unroll
    for (int i = 0; i < 6; ++i) {
        float te = 0.2f * (float)i;
        cbA[i] = erff((te - pda0) * inv);
        cpA[i] = erff((te - persA) * inv);
        cbB[i] = erff((te - pdb0) * inv);
        cpB[i] = erff((te - persB) * inv);
    }

    int lane = threadIdx.x & 63;
    int wv = threadIdx.x >> 6;
    __shared__ float sacc[4][25];
#pragma unroll
    for (int i = 0; i < 5; ++i) {
        float pa = 0.25f * persA * (cbA[i + 1] - cbA[i]);
        float pb = 0.25f * persB * (cbB[i + 1] - cbB[i]);
#pragma unroll
        for (int jj = 0; jj < 5; ++jj) {
            float v = pa * (cpA[jj + 1] - cpA[jj]) + pb * (cpB[jj + 1] - cpB[jj]);
            v += __shfl_down(v, 32);
            v += __shfl_down(v, 16);
            v += __shfl_down(v, 8);
            v += __shfl_down(v, 4);
            v += __shfl_down(v, 2);
            v += __shfl_down(v, 1);
            if (lane == 0) sacc[wv][i * 5 + jj] = v;
        }
    }
    __syncthreads();
    if (threadIdx.x < 25) {
        partial[(size_t)blockIdx.x * 25 + threadIdx.x] =
            sacc[0][threadIdx.x] + sacc[1][threadIdx.x] + sacc[2][threadIdx.x] + sacc[3][threadIdx.x];
    }
}

// ---- deterministic final reduction of block partials per bin ----
__global__ __launch_bounds__(256) void k_img(const float* __restrict__ partial, float* __restrict__ img) {
    int bin = blockIdx.x;  // 25 blocks
    float s = 0.f;
    for (int k = threadIdx.x; k < EE / 512; k += 256) s += partial[(size_t)k * 25 + bin];
    s += __shfl_down(s, 32);
    s += __shfl_down(s, 16);
    s += __shfl_down(s, 8);
    s += __shfl_down(s, 4);
    s += __shfl_down(s, 2);
    s += __shfl_down(s, 1);
    __shared__ float wsum[4];
    if ((threadIdx.x & 63) == 0) wsum[threadIdx.x >> 6] = s;
    __syncthreads();
    if (threadIdx.x == 0) img[bin] = wsum[0] + wsum[1] + wsum[2] + wsum[3];
}

extern "C" void kernel_launch(void* const* d_in, const int* in_sizes, int n_in,
                              void* d_out, int out_size, void* d_ws, size_t ws_size,
                              hipStream_t stream) {
    const float* x0 = (const float*)d_in[0];
    // Harness converts integer inputs to int32: edge_index0 is (2, ET) int32.
    const int* src32 = (const int*)d_in[1];
    const int* dst32 = src32 + ET;
    const float* W1 = (const float*)d_in[2];
    const float* b1 = (const float*)d_in[3];
    const float* W2 = (const float*)d_in[4];
    const float* b2 = (const float*)d_in[5];
    const float* W4 = (const float*)d_in[6];
    const float* b4 = (const float*)d_in[7];
    const float* W3 = (const float*)d_in[8];
    const float* b3 = (const float*)d_in[9];
    const float* W5 = (const float*)d_in[10];
    const float* b5 = (const float*)d_in[11];
    const float* W6 = (const float*)d_in[12];
    const float* b6 = (const float*)d_in[13];
    float* out = (float*)d_out;

    char* w = (char*)d_ws;
    int2* pairs = (int2*)w;                          // ET int2
    int* bucket_cnt = (int*)(pairs + ET);            // NBKT
    int* bucket_base = bucket_cnt + NBKT;            // NBKT+1
    int* bucket_fill = bucket_base + NBKT + 1;       // NBKT
    int* rowptr = bucket_fill + NBKT;                // NN+1
    int* src_sorted = rowptr + NN + 1;               // ET
    size_t off = ((size_t)((char*)(src_sorted + ET) - w) + 63) & ~(size_t)63;
    __half* bufA = (__half*)(w + off);               // NN*32 halfs
    __half* bufB = bufA + (size_t)NN * 32;           // NN*32 halfs
    __half* u16 = bufB + (size_t)NN * 32;            // NN*32 halfs
    __half* v16 = u16 + (size_t)NN * 32;             // NN*32 halfs
    float* agg0 = (float*)(v16 + (size_t)NN * 32);   // NN floats
    float* partial = agg0 + NN;                      // (EE/512)*25 floats

    // ---- build CSR via coarse-bucket counting sort ----
    k_zero<<<1, 128, 0, stream>>>(bucket_cnt, NBKT);
    k_bkt_count<<<NBLK_A, 256, 0, stream>>>(dst32, bucket_cnt);
    k_bkt_scan<<<1, 128, 0, stream>>>(bucket_cnt, bucket_base, bucket_fill);
    k_bkt_scatter<<<NBLK_A, 256, 0, stream>>>(src32, dst32, bucket_fill, pairs);
    k_bkt_csr<<<NBKT, 512, 0, stream>>>(pairs, bucket_base, rowptr, src_sorted);

    // ---- layer 1 ----
    k_pull1a<<<(NN + 255) / 256, 256, 0, stream>>>(rowptr, src_sorted, x0, agg0);
    k_pull1b<<<NN * 8 / 256, 256, 0, stream>>>(agg0, W1, b1, bufA);
    // ---- layers 2-3 (4 lanes/node, uint4 gathers) ----
    k_agg_mm<1><<<(NN * 4 + 255) / 256, 256, 0, stream>>>(rowptr, src_sorted, bufA, W2, b2, bufB);
    k_agg_mm<1><<<(NN * 4 + 255) / 256, 256, 0, stream>>>(rowptr, src_sorted, bufB, W4, b4, bufA);
    // ---- layer 4 + W5 projections ----
    k_agg_mm_proj<<<(NN * 4 + 255) / 256, 256, 0, stream>>>(rowptr, src_sorted, bufA, W3, b3, W5, b5, u16, v16);

    // ---- edge MLP + persistence image (original order) ----
    k_edge<<<EE / 512, 256, 0, stream>>>(src32, dst32, u16, v16, W6, b6, out, partial);
    k_img<<<25, 256, 0, stream>>>(partial, out + 2 * (size_t)EE);
}

// Round 11
// 242.627 us; speedup vs baseline: 1.0680x; 1.0453x over previous
//
#include <hip/hip_runtime.h>
#include <hip/hip_bf16.h>
#include <hip/hip_fp16.h>
#include <math.h>

#define NN 100000
#define EE 1600000
#define ET 1700000   // E + N self-loops
#define HID 32

#define BKT_SHIFT 10
#define BKT_MASK 1023
#define NBKT 98            // ceil(NN / 1024)
#define EPB 4096           // edges per block in stage A
#define NBLK_A 416         // ceil(ET / EPB)

// ---- zero small int buffer ----
__global__ __launch_bounds__(128) void k_zero(int* __restrict__ p, int n) {
    int t = blockIdx.x * 128 + threadIdx.x;
    if (t < n) p[t] = 0;
}

// ---- stage A0: coarse bucket counts (LDS hist, one global atomic per block-bin) ----
__global__ __launch_bounds__(256) void k_bkt_count(const int* __restrict__ dst32, int* __restrict__ bucket_cnt) {
    __shared__ int h[NBKT];
    for (int i = threadIdx.x; i < NBKT; i += 256) h[i] = 0;
    __syncthreads();
    int base = blockIdx.x * EPB;
    for (int k = 0; k < EPB; k += 256) {
        int t = base + k + threadIdx.x;
        if (t < ET) atomicAdd(&h[dst32[t] >> BKT_SHIFT], 1);
    }
    __syncthreads();
    for (int i = threadIdx.x; i < NBKT; i += 256) {
        int c = h[i];
        if (c) atomicAdd(&bucket_cnt[i], c);
    }
}

// ---- stage A scan: exclusive scan of 98 bucket counts ----
__global__ __launch_bounds__(128) void k_bkt_scan(const int* __restrict__ bucket_cnt, int* __restrict__ bucket_base,
                                                  int* __restrict__ bucket_fill) {
    __shared__ int s[128];
    int t = threadIdx.x;
    int v = (t < NBKT) ? bucket_cnt[t] : 0;
    s[t] = v;
    for (int off = 1; off < 128; off <<= 1) {
        __syncthreads();
        int u = (t >= off) ? s[t - off] : 0;
        __syncthreads();
        s[t] += u;
    }
    __syncthreads();
    int ex = s[t] - v;
    if (t < NBKT) {
        bucket_base[t] = ex;
        bucket_fill[t] = ex;
    }
    if (t == 0) bucket_base[NBKT] = ET;
}

// ---- stage A1: scatter (src,dst) pairs into coarse bucket regions ----
__global__ __launch_bounds__(256) void k_bkt_scatter(const int* __restrict__ src32, const int* __restrict__ dst32,
                                                     int* __restrict__ bucket_fill, int2* __restrict__ pairs) {
    __shared__ int h[NBKT];
    __shared__ int bbase[NBKT];
    for (int i = threadIdx.x; i < NBKT; i += 256) h[i] = 0;
    __syncthreads();
    int base = blockIdx.x * EPB;
    for (int k = 0; k < EPB; k += 256) {
        int t = base + k + threadIdx.x;
        if (t < ET) atomicAdd(&h[dst32[t] >> BKT_SHIFT], 1);
    }
    __syncthreads();
    for (int i = threadIdx.x; i < NBKT; i += 256) {
        int c = h[i];
        bbase[i] = c ? atomicAdd(&bucket_fill[i], c) : 0;
        h[i] = 0;  // becomes local fill counter (same thread owns bin -> no race)
    }
    __syncthreads();
    for (int k = 0; k < EPB; k += 256) {
        int t = base + k + threadIdx.x;
        if (t < ET) {
            int sv = src32[t], dv = dst32[t];
            int b = dv >> BKT_SHIFT;
            int off = atomicAdd(&h[b], 1);
            pairs[bbase[b] + off] = make_int2(sv, dv);
        }
    }
}

// ---- stage B: per-bucket fine CSR (1024 nodes in LDS) + in-bucket scatter of src ----
__global__ __launch_bounds__(512) void k_bkt_csr(const int2* __restrict__ pairs, const int* __restrict__ bucket_base,
                                                 int* __restrict__ rowptr, int* __restrict__ src_sorted) {
    __shared__ int h[1024];
    __shared__ int tmp[512];
    int t = threadIdx.x;
    int b = blockIdx.x;
    int e0 = bucket_base[b], e1 = bucket_base[b + 1];
    int node0 = b << BKT_SHIFT;

    h[t] = 0;
    h[t + 512] = 0;
    __syncthreads();
    for (int e = e0 + t; e < e1; e += 512) atomicAdd(&h[pairs[e].y & BKT_MASK], 1);
    __syncthreads();

    int i0 = 2 * t, i1 = 2 * t + 1;
    int v0 = h[i0], v1 = h[i1];
    int s = v0 + v1;
    tmp[t] = s;
    for (int off = 1; off < 512; off <<= 1) {
        __syncthreads();
        int u = (t >= off) ? tmp[t - off] : 0;
        __syncthreads();
        tmp[t] += u;
    }
    __syncthreads();
    int excl = tmp[t] - s;
    h[i0] = excl;
    h[i1] = excl + v0;
    __syncthreads();

    for (int i = t; i < 1024; i += 512) {
        int node = node0 + i;
        if (node < NN) rowptr[node] = e0 + h[i];
    }
    if (b == 0 && t == 0) rowptr[NN] = ET;
    __syncthreads();

    for (int e = e0 + t; e < e1; e += 512) {
        int2 p = pairs[e];
        int sl = atomicAdd(&h[p.y & BKT_MASK], 1);
        src_sorted[e0 + sl] = p.x;
    }
}

// ---- helpers ----
__device__ __forceinline__ void acc8(uint4 r, float* c) {
    float2 f0 = __half22float2(*reinterpret_cast<__half2*>(&r.x));
    float2 f1 = __half22float2(*reinterpret_cast<__half2*>(&r.y));
    float2 f2 = __half22float2(*reinterpret_cast<__half2*>(&r.z));
    float2 f3 = __half22float2(*reinterpret_cast<__half2*>(&r.w));
    c[0] += f0.x; c[1] += f0.y; c[2] += f1.x; c[3] += f1.y;
    c[4] += f2.x; c[5] += f2.y; c[6] += f3.x; c[7] += f3.y;
}

// ---- layer 1 fused: thread-per-node scalar pull-agg + 1->32 linear + relu -> fp16 row ----
__global__ __launch_bounds__(256) void k_pull1(const int* __restrict__ rowptr, const int* __restrict__ src_sorted,
                                               const float* __restrict__ x0, const float* __restrict__ W1,
                                               const float* __restrict__ b1, __half* __restrict__ hout) {
    __shared__ float W1l[32], b1l[32];
    if (threadIdx.x < 32) {
        W1l[threadIdx.x] = W1[threadIdx.x];
        b1l[threadIdx.x] = b1[threadIdx.x];
    }
    __syncthreads();
    int g = blockIdx.x * 256 + threadIdx.x;
    if (g >= NN) return;
    int e0 = rowptr[g], e1 = rowptr[g + 1];
    float a0 = x0[g], a1 = 0.f, a2 = 0.f, a3 = 0.f, a4 = 0.f, a5 = 0.f, a6 = 0.f, a7 = 0.f;
    int e = e0;
    for (; e + 8 <= e1; e += 8) {
        a0 += x0[src_sorted[e + 0]];
        a1 += x0[src_sorted[e + 1]];
        a2 += x0[src_sorted[e + 2]];
        a3 += x0[src_sorted[e + 3]];
        a4 += x0[src_sorted[e + 4]];
        a5 += x0[src_sorted[e + 5]];
        a6 += x0[src_sorted[e + 6]];
        a7 += x0[src_sorted[e + 7]];
    }
    for (; e < e1; ++e) a0 += x0[src_sorted[e]];
    float s = ((a0 + a1) + (a2 + a3)) + ((a4 + a5) + (a6 + a7));

    uint4* orow = reinterpret_cast<uint4*>(hout) + ((size_t)g << 2);
#pragma unroll
    for (int q = 0; q < 4; ++q) {
        float o0 = fmaxf(fmaf(s, W1l[8 * q + 0], b1l[8 * q + 0]), 0.f);
        float o1 = fmaxf(fmaf(s, W1l[8 * q + 1], b1l[8 * q + 1]), 0.f);
        float o2 = fmaxf(fmaf(s, W1l[8 * q + 2], b1l[8 * q + 2]), 0.f);
        float o3 = fmaxf(fmaf(s, W1l[8 * q + 3], b1l[8 * q + 3]), 0.f);
        float o4 = fmaxf(fmaf(s, W1l[8 * q + 4], b1l[8 * q + 4]), 0.f);
        float o5 = fmaxf(fmaf(s, W1l[8 * q + 5], b1l[8 * q + 5]), 0.f);
        float o6 = fmaxf(fmaf(s, W1l[8 * q + 6], b1l[8 * q + 6]), 0.f);
        float o7 = fmaxf(fmaf(s, W1l[8 * q + 7], b1l[8 * q + 7]), 0.f);
        __half2 p0 = __floats2half2_rn(o0, o1);
        __half2 p1 = __floats2half2_rn(o2, o3);
        __half2 p2 = __floats2half2_rn(o4, o5);
        __half2 p3 = __floats2half2_rn(o6, o7);
        orow[q] = make_uint4(*reinterpret_cast<unsigned*>(&p0), *reinterpret_cast<unsigned*>(&p1),
                             *reinterpret_cast<unsigned*>(&p2), *reinterpret_cast<unsigned*>(&p3));
    }
}

// ---- fused pull-agg + 32x32 matmul (+relu), 4 lanes/node, uint4 gathers, 8-deep ILP ----
template <int RELU>
__global__ __launch_bounds__(256) void k_agg_mm(const int* __restrict__ rowptr, const int* __restrict__ src_sorted,
                                                const __half* __restrict__ hin, const float* __restrict__ W,
                                                const float* __restrict__ b, __half* __restrict__ hout) {
    __shared__ float Wl[1024];
    for (int i = threadIdx.x; i < 1024; i += 256) Wl[i] = W[i];
    __syncthreads();
    int g = (blockIdx.x * 256 + threadIdx.x) >> 2;   // 64 nodes/block
    if (g >= NN) return;
    int j = threadIdx.x & 3;
    const uint4* tab = reinterpret_cast<const uint4*>(hin);
    int e0 = rowptr[g], e1 = rowptr[g + 1];
    float x[8], y[8];
#pragma unroll
    for (int i = 0; i < 8; ++i) { x[i] = 0.f; y[i] = 0.f; }
    acc8(tab[(g << 2) + j], x);  // self term
    int e = e0;
    for (; e + 8 <= e1; e += 8) {
        int s0 = src_sorted[e + 0], s1 = src_sorted[e + 1], s2 = src_sorted[e + 2], s3 = src_sorted[e + 3];
        int s4 = src_sorted[e + 4], s5 = src_sorted[e + 5], s6 = src_sorted[e + 6], s7 = src_sorted[e + 7];
        uint4 r0 = tab[(s0 << 2) + j];
        uint4 r1 = tab[(s1 << 2) + j];
        uint4 r2 = tab[(s2 << 2) + j];
        uint4 r3 = tab[(s3 << 2) + j];
        uint4 r4 = tab[(s4 << 2) + j];
        uint4 r5 = tab[(s5 << 2) + j];
        uint4 r6 = tab[(s6 << 2) + j];
        uint4 r7 = tab[(s7 << 2) + j];
        acc8(r0, x); acc8(r1, y); acc8(r2, x); acc8(r3, y);
        acc8(r4, x); acc8(r5, y); acc8(r6, x); acc8(r7, y);
    }
    for (; e < e1; ++e) acc8(tab[(src_sorted[e] << 2) + j], x);
#pragma unroll
    for (int i = 0; i < 8; ++i) x[i] += y[i];

    float o[8];
#pragma unroll
    for (int i = 0; i < 8; ++i) o[i] = b[8 * j + i];
#pragma unroll
    for (int sl = 0; sl < 4; ++sl) {
#pragma unroll
        for (int r = 0; r < 8; ++r) {
            float xk = __shfl(x[r], sl, 4);
            int k = 8 * sl + r;
            float4 w0 = *reinterpret_cast<const float4*>(&Wl[k * 32 + 8 * j]);
            float4 w1 = *reinterpret_cast<const float4*>(&Wl[k * 32 + 8 * j + 4]);
            o[0] = fmaf(xk, w0.x, o[0]); o[1] = fmaf(xk, w0.y, o[1]);
            o[2] = fmaf(xk, w0.z, o[2]); o[3] = fmaf(xk, w0.w, o[3]);
            o[4] = fmaf(xk, w1.x, o[4]); o[5] = fmaf(xk, w1.y, o[5]);
            o[6] = fmaf(xk, w1.z, o[6]); o[7] = fmaf(xk, w1.w, o[7]);
        }
    }
    if (RELU) {
#pragma unroll
        for (int i = 0; i < 8; ++i) o[i] = fmaxf(o[i], 0.f);
    }
    __half2 p0 = __floats2half2_rn(o[0], o[1]);
    __half2 p1 = __floats2half2_rn(o[2], o[3]);
    __half2 p2 = __floats2half2_rn(o[4], o[5]);
    __half2 p3 = __floats2half2_rn(o[6], o[7]);
    uint4 st = make_uint4(*reinterpret_cast<unsigned*>(&p0), *reinterpret_cast<unsigned*>(&p1),
                          *reinterpret_cast<unsigned*>(&p2), *reinterpret_cast<unsigned*>(&p3));
    reinterpret_cast<uint4*>(hout)[(g << 2) + j] = st;
}

// ---- layer 4 fused: pull-agg + W3 matmul + W5 projections -> u16 (b5 folded), v16 ----
__global__ __launch_bounds__(256) void k_agg_mm_proj(const int* __restrict__ rowptr, const int* __restrict__ src_sorted,
                                                     const __half* __restrict__ hin, const float* __restrict__ W3,
                                                     const float* __restrict__ b3,
                                                     const float* __restrict__ W5, const float* __restrict__ b5,
                                                     __half* __restrict__ u16, __half* __restrict__ v16) {
    __shared__ float W3l[1024];
    __shared__ float W5l[2048];
    for (int i = threadIdx.x; i < 1024; i += 256) W3l[i] = W3[i];
    for (int i = threadIdx.x; i < 2048; i += 256) W5l[i] = W5[i];
    __syncthreads();
    int g = (blockIdx.x * 256 + threadIdx.x) >> 2;
    if (g >= NN) return;
    int j = threadIdx.x & 3;
    const uint4* tab = reinterpret_cast<const uint4*>(hin);
    int e0 = rowptr[g], e1 = rowptr[g + 1];
    float x[8], y[8];
#pragma unroll
    for (int i = 0; i < 8; ++i) { x[i] = 0.f; y[i] = 0.f; }
    acc8(tab[(g << 2) + j], x);  // self term
    int e = e0;
    for (; e + 8 <= e1; e += 8) {
        int s0 = src_sorted[e + 0], s1 = src_sorted[e + 1], s2 = src_sorted[e + 2], s3 = src_sorted[e + 3];
        int s4 = src_sorted[e + 4], s5 = src_sorted[e + 5], s6 = src_sorted[e + 6], s7 = src_sorted[e + 7];
        uint4 r0 = tab[(s0 << 2) + j];
        uint4 r1 = tab[(s1 << 2) + j];
        uint4 r2 = tab[(s2 << 2) + j];
        uint4 r3 = tab[(s3 << 2) + j];
        uint4 r4 = tab[(s4 << 2) + j];
        uint4 r5 = tab[(s5 << 2) + j];
        uint4 r6 = tab[(s6 << 2) + j];
        uint4 r7 = tab[(s7 << 2) + j];
        acc8(r0, x); acc8(r1, y); acc8(r2, x); acc8(r3, y);
        acc8(r4, x); acc8(r5, y); acc8(r6, x); acc8(r7, y);
    }
    for (; e < e1; ++e) acc8(tab[(src_sorted[e] << 2) + j], x);
#pragma unroll
    for (int i = 0; i < 8; ++i) x[i] += y[i];

    // x4 = agg . W3 + b3 (no relu)
    float o[8];
#pragma unroll
    for (int i = 0; i < 8; ++i) o[i] = b3[8 * j + i];
#pragma unroll
    for (int sl = 0; sl < 4; ++sl) {
#pragma unroll
        for (int r = 0; r < 8; ++r) {
            float xk = __shfl(x[r], sl, 4);
            int k = 8 * sl + r;
            float4 w0 = *reinterpret_cast<const float4*>(&W3l[k * 32 + 8 * j]);
            float4 w1 = *reinterpret_cast<const float4*>(&W3l[k * 32 + 8 * j + 4]);
            o[0] = fmaf(xk, w0.x, o[0]); o[1] = fmaf(xk, w0.y, o[1]);
            o[2] = fmaf(xk, w0.z, o[2]); o[3] = fmaf(xk, w0.w, o[3]);
            o[4] = fmaf(xk, w1.x, o[4]); o[5] = fmaf(xk, w1.y, o[5]);
            o[6] = fmaf(xk, w1.z, o[6]); o[7] = fmaf(xk, w1.w, o[7]);
        }
    }
    // u = x4 . W5[0:32,:] + b5 ; v = x4 . W5[32:64,:]
    float u[8], v[8];
#pragma unroll
    for (int i = 0; i < 8; ++i) { u[i] = b5[8 * j + i]; v[i] = 0.f; }
#pragma unroll
    for (int sl = 0; sl < 4; ++sl) {
#pragma unroll
        for (int r = 0; r < 8; ++r) {
            float xk = __shfl(o[r], sl, 4);
            int k = 8 * sl + r;
            float4 a0 = *reinterpret_cast<const float4*>(&W5l[k * 32 + 8 * j]);
            float4 a1 = *reinterpret_cast<const float4*>(&W5l[k * 32 + 8 * j + 4]);
            u[0] = fmaf(xk, a0.x, u[0]); u[1] = fmaf(xk, a0.y, u[1]);
            u[2] = fmaf(xk, a0.z, u[2]); u[3] = fmaf(xk, a0.w, u[3]);
            u[4] = fmaf(xk, a1.x, u[4]); u[5] = fmaf(xk, a1.y, u[5]);
            u[6] = fmaf(xk, a1.z, u[6]); u[7] = fmaf(xk, a1.w, u[7]);
            float4 c0 = *reinterpret_cast<const float4*>(&W5l[(32 + k) * 32 + 8 * j]);
            float4 c1 = *reinterpret_cast<const float4*>(&W5l[(32 + k) * 32 + 8 * j + 4]);
            v[0] = fmaf(xk, c0.x, v[0]); v[1] = fmaf(xk, c0.y, v[1]);
            v[2] = fmaf(xk, c0.z, v[2]); v[3] = fmaf(xk, c0.w, v[3]);
            v[4] = fmaf(xk, c1.x, v[4]); v[5] = fmaf(xk, c1.y, v[5]);
            v[6] = fmaf(xk, c1.z, v[6]); v[7] = fmaf(xk, c1.w, v[7]);
        }
    }
    __half2 pu0 = __floats2half2_rn(u[0], u[1]);
    __half2 pu1 = __floats2half2_rn(u[2], u[3]);
    __half2 pu2 = __floats2half2_rn(u[4], u[5]);
    __half2 pu3 = __floats2half2_rn(u[6], u[7]);
    uint4 su = make_uint4(*reinterpret_cast<unsigned*>(&pu0), *reinterpret_cast<unsigned*>(&pu1),
                          *reinterpret_cast<unsigned*>(&pu2), *reinterpret_cast<unsigned*>(&pu3));
    reinterpret_cast<uint4*>(u16)[(g << 2) + j] = su;
    __half2 pv0 = __floats2half2_rn(v[0], v[1]);
    __half2 pv1 = __floats2half2_rn(v[2], v[3]);
    __half2 pv2 = __floats2half2_rn(v[4], v[5]);
    __half2 pv3 = __floats2half2_rn(v[6], v[7]);
    uint4 sv = make_uint4(*reinterpret_cast<unsigned*>(&pv0), *reinterpret_cast<unsigned*>(&pv1),
                          *reinterpret_cast<unsigned*>(&pv2), *reinterpret_cast<unsigned*>(&pv3));
    reinterpret_cast<uint4*>(v16)[(g << 2) + j] = sv;
}

// ---- per-edge (2 edges/thread): ALL 16 row-loads hoisted & fenced, then compute ----
__global__ __launch_bounds__(256) void k_edge(const int* __restrict__ src32, const int* __restrict__ dst32,
                                              const __half* __restrict__ u16, const __half* __restrict__ v16,
                                              const float* __restrict__ W6, const float* __restrict__ b6,
                                              float* __restrict__ pd_out, float* __restrict__ partial) {
    int ea = blockIdx.x * 512 + threadIdx.x;   // EE divisible by 512
    int eb = ea + 256;
    int sa = src32[ea], da = dst32[ea];
    int sb = src32[eb], db = dst32[eb];
    const uint4* pua = reinterpret_cast<const uint4*>(u16 + ((size_t)sa << 5));
    const uint4* pva = reinterpret_cast<const uint4*>(v16 + ((size_t)da << 5));
    const uint4* pub = reinterpret_cast<const uint4*>(u16 + ((size_t)sb << 5));
    const uint4* pvb = reinterpret_cast<const uint4*>(v16 + ((size_t)db << 5));

    // hoist all 16 16B gathers into registers; fence so the compiler can't sink them
    uint4 A[4], B[4], C[4], D[4];
#pragma unroll
    for (int q = 0; q < 4; ++q) A[q] = pua[q];
#pragma unroll
    for (int q = 0; q < 4; ++q) B[q] = pva[q];
#pragma unroll
    for (int q = 0; q < 4; ++q) C[q] = pub[q];
#pragma unroll
    for (int q = 0; q < 4; ++q) D[q] = pvb[q];
    __builtin_amdgcn_sched_barrier(0);

    float b60 = b6[0], b61 = b6[1];
    float pda0 = b60, pda1 = b61, pdb0 = b60, pdb1 = b61;
#pragma unroll
    for (int q = 0; q < 4; ++q) {
        const __half2* ah = reinterpret_cast<const __half2*>(&A[q]);
        const __half2* bh = reinterpret_cast<const __half2*>(&B[q]);
        const __half2* ch = reinterpret_cast<const __half2*>(&C[q]);
        const __half2* dh = reinterpret_cast<const __half2*>(&D[q]);
#pragma unroll
        for (int r = 0; r < 4; ++r) {
            float2 fA = __half22float2(__hadd2(ah[r], bh[r]));
            float2 fB = __half22float2(__hadd2(ch[r], dh[r]));
            int jj = q * 8 + 2 * r;
            float w00 = W6[2 * jj + 0], w01 = W6[2 * jj + 1];
            float w10 = W6[2 * (jj + 1) + 0], w11 = W6[2 * (jj + 1) + 1];
            float hA0 = fA.x >= 0.f ? fA.x : 0.1f * fA.x;
            float hA1 = fA.y >= 0.f ? fA.y : 0.1f * fA.y;
            float hB0 = fB.x >= 0.f ? fB.x : 0.1f * fB.x;
            float hB1 = fB.y >= 0.f ? fB.y : 0.1f * fB.y;
            pda0 = fmaf(hA0, w00, pda0); pda1 = fmaf(hA0, w01, pda1);
            pda0 = fmaf(hA1, w10, pda0); pda1 = fmaf(hA1, w11, pda1);
            pdb0 = fmaf(hB0, w00, pdb0); pdb1 = fmaf(hB0, w01, pdb1);
            pdb0 = fmaf(hB1, w10, pdb0); pdb1 = fmaf(hB1, w11, pdb1);
        }
    }
    reinterpret_cast<float2*>(pd_out)[ea] = make_float2(pda0, pda1);
    reinterpret_cast<float2*>(pd_out)[eb] = make_float2(pdb0, pdb1);

    float persA = pda1 - pda0;
    float persB = pdb1 - pdb0;
    const float inv = 3.5355339059327378f;  // 1/(0.2*sqrt(2))
    float cbA[6], cpA[6], cbB[6], cpB[6];
#pragma unroll
    for (int i = 0; i < 6; ++i) {
        float te = 0.2f * (float)i;
        cbA[i] = erff((te - pda0) * inv);
        cpA[i] = erff((te - persA) * inv);
        cbB[i] = erff((te - pdb0) * inv);
        cpB[i] = erff((te - persB) * inv);
    }

    int lane = threadIdx.x & 63;
    int wv = threadIdx.x >> 6;
    __shared__ float sacc[4][25];
#pragma unroll
    for (int i = 0; i < 5; ++i) {
        float pa = 0.25f * persA * (cbA[i + 1] - cbA[i]);
        float pb = 0.25f * persB * (cbB[i + 1] - cbB[i]);
#pragma unroll
        for (int jj = 0; jj < 5; ++jj) {
            float v = pa * (cpA[jj + 1] - cpA[jj]) + pb * (cpB[jj + 1] - cpB[jj]);
            v += __shfl_down(v, 32);
            v += __shfl_down(v, 16);
            v += __shfl_down(v, 8);
            v += __shfl_down(v, 4);
            v += __shfl_down(v, 2);
            v += __shfl_down(v, 1);
            if (lane == 0) sacc[wv][i * 5 + jj] = v;
        }
    }
    __syncthreads();
    if (threadIdx.x < 25) {
        partial[(size_t)blockIdx.x * 25 + threadIdx.x] =
            sacc[0][threadIdx.x] + sacc[1][threadIdx.x] + sacc[2][threadIdx.x] + sacc[3][threadIdx.x];
    }
}

// ---- deterministic final reduction of block partials per bin ----
__global__ __launch_bounds__(256) void k_img(const float* __restrict__ partial, float* __restrict__ img) {
    int bin = blockIdx.x;  // 25 blocks
    float s = 0.f;
    for (int k = threadIdx.x; k < EE / 512; k += 256) s += partial[(size_t)k * 25 + bin];
    s += __shfl_down(s, 32);
    s += __shfl_down(s, 16);
    s += __shfl_down(s, 8);
    s += __shfl_down(s, 4);
    s += __shfl_down(s, 2);
    s += __shfl_down(s, 1);
    __shared__ float wsum[4];
    if ((threadIdx.x & 63) == 0) wsum[threadIdx.x >> 6] = s;
    __syncthreads();
    if (threadIdx.x == 0) img[bin] = wsum[0] + wsum[1] + wsum[2] + wsum[3];
}

extern "C" void kernel_launch(void* const* d_in, const int* in_sizes, int n_in,
                              void* d_out, int out_size, void* d_ws, size_t ws_size,
                              hipStream_t stream) {
    const float* x0 = (const float*)d_in[0];
    // Harness converts integer inputs to int32: edge_index0 is (2, ET) int32.
    const int* src32 = (const int*)d_in[1];
    const int* dst32 = src32 + ET;
    const float* W1 = (const float*)d_in[2];
    const float* b1 = (const float*)d_in[3];
    const float* W2 = (const float*)d_in[4];
    const float* b2 = (const float*)d_in[5];
    const float* W4 = (const float*)d_in[6];
    const float* b4 = (const float*)d_in[7];
    const float* W3 = (const float*)d_in[8];
    const float* b3 = (const float*)d_in[9];
    const float* W5 = (const float*)d_in[10];
    const float* b5 = (const float*)d_in[11];
    const float* W6 = (const float*)d_in[12];
    const float* b6 = (const float*)d_in[13];
    float* out = (float*)d_out;

    char* w = (char*)d_ws;
    int2* pairs = (int2*)w;                          // ET int2
    int* bucket_cnt = (int*)(pairs + ET);            // NBKT
    int* bucket_base = bucket_cnt + NBKT;            // NBKT+1
    int* bucket_fill = bucket_base + NBKT + 1;       // NBKT
    int* rowptr = bucket_fill + NBKT;                // NN+1
    int* src_sorted = rowptr + NN + 1;               // ET
    size_t off = ((size_t)((char*)(src_sorted + ET) - w) + 63) & ~(size_t)63;
    __half* bufA = (__half*)(w + off);               // NN*32 halfs
    __half* bufB = bufA + (size_t)NN * 32;           // NN*32 halfs
    __half* u16 = bufB + (size_t)NN * 32;            // NN*32 halfs
    __half* v16 = u16 + (size_t)NN * 32;             // NN*32 halfs
    float* partial = (float*)(v16 + (size_t)NN * 32);// (EE/512)*25 floats

    // ---- build CSR via coarse-bucket counting sort ----
    k_zero<<<1, 128, 0, stream>>>(bucket_cnt, NBKT);
    k_bkt_count<<<NBLK_A, 256, 0, stream>>>(dst32, bucket_cnt);
    k_bkt_scan<<<1, 128, 0, stream>>>(bucket_cnt, bucket_base, bucket_fill);
    k_bkt_scatter<<<NBLK_A, 256, 0, stream>>>(src32, dst32, bucket_fill, pairs);
    k_bkt_csr<<<NBKT, 512, 0, stream>>>(pairs, bucket_base, rowptr, src_sorted);

    // ---- layer 1 (fused agg + expand) ----
    k_pull1<<<(NN + 255) / 256, 256, 0, stream>>>(rowptr, src_sorted, x0, W1, b1, bufA);
    // ---- layers 2-3 (4 lanes/node, uint4 gathers) ----
    k_agg_mm<1><<<(NN * 4 + 255) / 256, 256, 0, stream>>>(rowptr, src_sorted, bufA, W2, b2, bufB);
    k_agg_mm<1><<<(NN * 4 + 255) / 256, 256, 0, stream>>>(rowptr, src_sorted, bufB, W4, b4, bufA);
    // ---- layer 4 + W5 projections ----
    k_agg_mm_proj<<<(NN * 4 + 255) / 256, 256, 0, stream>>>(rowptr, src_sorted, bufA, W3, b3, W5, b5, u16, v16);

    // ---- edge MLP + persistence image (original order) ----
    k_edge<<<EE / 512, 256, 0, stream>>>(src32, dst32, u16, v16, W6, b6, out, partial);
    k_img<<<25, 256, 0, stream>>>(partial, out + 2 * (size_t)EE);
}